// Round 15
// baseline (2305.825 us; speedup 1.0000x reference)
//
#include <hip/hip_runtime.h>
#include <stdint.h>

#define MDIM 4096
#define KDIM 4096
#define NDIM 11008
#define KP   (KDIM/8)    // 512 packed int32 per N-row

typedef float  f32x4   __attribute__((ext_vector_type(4)));
typedef __bf16 bf16x8  __attribute__((ext_vector_type(8)));
typedef unsigned short u16x8 __attribute__((ext_vector_type(8)));
typedef int    i32x4   __attribute__((ext_vector_type(4)));
typedef int    i32x16  __attribute__((ext_vector_type(16)));
typedef char   c8x8    __attribute__((ext_vector_type(8)));
typedef char   c8x16   __attribute__((ext_vector_type(16)));

// RNE f32 -> bf16 bits (matches jax astype(bf16) for non-NaN inputs)
__device__ __forceinline__ unsigned short f2bf(float f) {
  uint32_t u = __builtin_bit_cast(uint32_t, f);
  u += 0x7FFFu + ((u >> 16) & 1u);
  return (unsigned short)(u >> 16);
}
__device__ __forceinline__ float bf2f(unsigned short h) {
  return __builtin_bit_cast(float, (uint32_t)h << 16);
}
__device__ __forceinline__ float bf16r(float f) { return bf2f(f2bf(f)); }

// async global -> LDS, 16B per lane, wave-uniform LDS base + lane*16
__device__ __forceinline__ void lds16(const void* g, void* l) {
  __builtin_amdgcn_global_load_lds(
      (const __attribute__((address_space(1))) unsigned int*)g,
      (__attribute__((address_space(3))) unsigned int*)l, 16, 0, 0);
}

// ---------------- pre-pass 1: unpack int4 words -> int8 Q8[N][K] ------------
__global__ __launch_bounds__(256) void repack_q_kernel(
    const uint32_t* __restrict__ wq, c8x8* __restrict__ Q8) {
  int idx = blockIdx.x * 256 + threadIdx.x;   // [0, N*KP)
  uint32_t w = wq[idx];
  c8x8 v;
#pragma unroll
  for (int j = 0; j < 8; ++j) v[j] = (char)((w >> (4 * j)) & 0xF);
  Q8[idx] = v;
}

// ---------------- pre-pass 2: x f32 -> per-row int8 + delta + exact bf16 sum
__global__ __launch_bounds__(256) void quant_x_kernel(
    const float* __restrict__ x, c8x16* __restrict__ X8,
    float* __restrict__ delta, float* __restrict__ xsum) {
  __shared__ float red[256];
  const int row = blockIdx.x, t = threadIdx.x;
  const float4* xr = (const float4*)(x + (size_t)row * KDIM);
  float xb[16];
#pragma unroll
  for (int i = 0; i < 4; ++i) {
    float4 f = xr[t * 4 + i];
    xb[i * 4 + 0] = bf16r(f.x); xb[i * 4 + 1] = bf16r(f.y);
    xb[i * 4 + 2] = bf16r(f.z); xb[i * 4 + 3] = bf16r(f.w);
  }
  float mx = 0.f, sm = 0.f;
#pragma unroll
  for (int j = 0; j < 16; ++j) { mx = fmaxf(mx, fabsf(xb[j])); sm += xb[j]; }
  red[t] = mx; __syncthreads();
  for (int o = 128; o > 0; o >>= 1) {
    if (t < o) red[t] = fmaxf(red[t], red[t + o]);
    __syncthreads();
  }
  const float rmx = red[0];
  __syncthreads();
  red[t] = sm; __syncthreads();
  for (int o = 128; o > 0; o >>= 1) {
    if (t < o) red[t] += red[t + o];
    __syncthreads();
  }
  const float rsm = red[0];
  const float inv = (rmx > 0.f) ? 127.0f / rmx : 0.f;
  if (t == 0) {
    delta[row] = (rmx > 0.f) ? rmx / 127.0f : 0.f;
    xsum[row]  = rsm;
  }
  c8x16 q;
#pragma unroll
  for (int j = 0; j < 16; ++j) q[j] = (char)__float2int_rn(xb[j] * inv);
  X8[(size_t)row * 256 + t] = q;
}

// ---------------- main GEMM: 256x256, 4 waves, i8 32x32x32, 2 blocks/CU -----
// Combines the three requirements isolated by r10-r14:
//  (a) reads/MFMA = 0.5 (r13 geometry: 4 waves x 128x128 output);
//  (b) 2 blocks/CU via 64KB LDS (2-slot shallow ring) — independent barrier
//      domains fill each other's vmcnt/barrier windows (r12 mechanism);
//  (c) minimal sync: 2 barriers/tile (32 MFMA per barrier).
// Fixed slot mapping (slot = K-half): (T,h1) staged at p0, first read at p2
// — retired by VMWAIT(0)+BAR at p1; (T+1,h0) staged at p2, first read at
// next tile's p0 — retired by VMWAIT(0)+BAR at p3. WAR on slot overwrite is
// safe: the previous reader's ds_reads complete (lgkm) before its MFMAs,
// which precede the barrier the stager has also passed (r10-proven argument).
// Staging/read addressing + epilogue VERBATIM r13 (passed, 0 bank conflicts).
// Per-CU budget: MFMA 83us > LDS ~73us -> MFMA-bound with 2-block overlap.
__global__ __launch_bounds__(256, 2) void gemm_i8_kernel(
    const char* __restrict__ A8, const char* __restrict__ Q8,
    const float* __restrict__ delta, const float* __restrict__ xsum,
    const float* __restrict__ scales, const float* __restrict__ zeros,
    const float* __restrict__ bias, float* __restrict__ out) {
  __shared__ __align__(16) char smem[65536];  // 2 slots x (A 16KB | B 16KB)

  const int tid  = threadIdx.x;
  const int lane = tid & 63;
  const int wave = tid >> 6;     // 0..3
  const int wm   = wave >> 1;    // 0..1 : M half (128 rows)
  const int wn   = wave & 1;     // 0..1 : N half (128 cols)

  // XCD-aware bijective swizzle: 688 = 8 * 86 blocks (verbatim).
  const int b   = blockIdx.x;
  const int swz = (b & 7) * 86 + (b >> 3);
  const int mt  = swz / 43;
  const int nt  = swz - mt * 43;
  const int bm0 = mt * 256, bn0 = nt * 256;

  // staging (r13 pattern, verbatim): lane l writes subtile bytes [l*16,+16);
  // stored position schunk holds global chunk schunk ^ (b3(srow)<<1) ^ (j&1).
  // Wave stages subtiles 4*wave + j (j=0..3) of each operand.
  const int srow   = lane >> 2;
  const int schunk = lane & 3;
  const int p0c    = schunk ^ (((srow >> 3) & 1) << 1);
  const char* aRe = A8 + (size_t)(bm0 + wave * 64 + srow) * KDIM + (size_t)(p0c * 16);
  const char* aRo = A8 + (size_t)(bm0 + wave * 64 + srow) * KDIM + (size_t)((p0c ^ 1) * 16);
  const char* bRe = Q8 + (size_t)(bn0 + wave * 64 + srow) * KDIM + (size_t)(p0c * 16);
  const char* bRo = Q8 + (size_t)(bn0 + wave * 64 + srow) * KDIM + (size_t)((p0c ^ 1) * 16);

  // fragment read offsets (r10/r13-proven zero-conflict pattern)
  const int r31 = lane & 31;
  const int sub = r31 >> 4;
  const int r15 = r31 & 15;
  const int hk  = lane >> 5;
  const int rd0 = sub * 1024 + r15 * 64 + ((hk ^ sub) << 4) + ((r15 & 8) << 2);
  const int rd1 = rd0 ^ 32;

  i32x16 acc[4][4];
#pragma unroll
  for (int i = 0; i < 4; ++i)
#pragma unroll
    for (int j = 0; j < 4; ++j)
#pragma unroll
      for (int r = 0; r < 16; ++r) acc[i][j][r] = 0;

  i32x4 Af[4], Bf[4];

#define SLOTB(S) ((S) * 32768)

// stage A(16KB)+B(16KB) of K-half (t,h) into slot S: 8 lds16/wave
#define STAGE_AB(t, h, S)                                                   \
  do {                                                                      \
    const size_t ko_ = (size_t)(t) * 128 + (size_t)(h) * 64;                \
    char* da_ = smem + SLOTB(S) + wave * 4096;                              \
    char* db_ = da_ + 16384;                                                \
    _Pragma("unroll") for (int j = 0; j < 4; ++j) {                         \
      lds16(((j & 1) ? aRo : aRe) + (size_t)j * 16 * KDIM + ko_,            \
            da_ + j * 1024);                                                \
      lds16(((j & 1) ? bRo : bRe) + (size_t)j * 16 * KDIM + ko_,            \
            db_ + j * 1024);                                                \
    }                                                                       \
  } while (0)

#define READ8(S, KS)                                                        \
  do {                                                                      \
    const int ro_ = (KS) ? rd1 : rd0;                                       \
    _Pragma("unroll") for (int mf = 0; mf < 4; ++mf)                        \
        Af[mf] = *(const i32x4*)(smem + SLOTB(S) + wm * 8192 +              \
                                 mf * 2048 + ro_);                          \
    _Pragma("unroll") for (int nf = 0; nf < 4; ++nf)                        \
        Bf[nf] = *(const i32x4*)(smem + SLOTB(S) + 16384 + wn * 8192 +      \
                                 nf * 2048 + ro_);                          \
  } while (0)

#define MFMA16()                                                            \
  __builtin_amdgcn_s_setprio(1);                                            \
  _Pragma("unroll") for (int mf = 0; mf < 4; ++mf)                          \
      _Pragma("unroll") for (int nf = 0; nf < 4; ++nf)                      \
          acc[mf][nf] = __builtin_amdgcn_mfma_i32_32x32x32_i8(              \
              Af[mf], Bf[nf], acc[mf][nf], 0, 0, 0);                        \
  __builtin_amdgcn_s_setprio(0);

#define BAR                                                                 \
  __builtin_amdgcn_s_barrier();                                             \
  __builtin_amdgcn_sched_barrier(0);

#define VMWAIT0 asm volatile("s_waitcnt vmcnt(0)" ::: "memory")

  // prologue: (0,h0) -> slot0
  STAGE_AB(0, 0, 0);
  VMWAIT0;
  BAR;

  for (int t = 0; t < 32; ++t) {
    // p0+p1: consume slot0 = (t,h0); stage (t,h1) -> slot1
    READ8(0, 0);
    STAGE_AB(t, 1, 1);
    MFMA16();
    READ8(0, 1);
    MFMA16();
    VMWAIT0;             // retire (t,h1) before p2 reads it
    BAR;
    // p2+p3: consume slot1 = (t,h1); stage (t+1,h0) -> slot0
    READ8(1, 0);
    if (t < 31) STAGE_AB(t + 1, 0, 0);
    MFMA16();
    READ8(1, 1);
    MFMA16();
    VMWAIT0;             // retire (t+1,h0) before next p0 reads it
    BAR;
  }

#undef VMWAIT0
#undef BAR
#undef MFMA16
#undef READ8
#undef STAGE_AB
#undef SLOTB

  // epilogue (verbatim r13): C/D 32x32 layout col=lane&31,
  // row=(reg&3)+8*(reg>>2)+4*(lane>>5).
  // out = acc * (Delta_m * bf16(s_n)) + bf16(z_n) * xsum_m + bias_n
  const int colv = bn0 + wn * 128 + (lane & 31);
  const int rowb = bm0 + wm * 128 + ((lane >> 5) << 2);
  float sb[4], zb[4], bv[4];
#pragma unroll
  for (int nf = 0; nf < 4; ++nf) {
    sb[nf] = bf16r(scales[colv + nf * 32]);
    zb[nf] = bf16r(zeros[colv + nf * 32]);
    bv[nf] = bias[colv + nf * 32];
  }
#pragma unroll
  for (int mf = 0; mf < 4; ++mf)
#pragma unroll
    for (int reg = 0; reg < 16; ++reg) {
      const int row = rowb + mf * 32 + (reg & 3) + ((reg >> 2) << 3);
      const float dm = delta[row];
      const float xm = xsum[row];
#pragma unroll
      for (int nf = 0; nf < 4; ++nf)
        out[(size_t)row * NDIM + colv + nf * 32] =
            (float)acc[mf][nf][reg] * (dm * sb[nf]) + (zb[nf] * xm + bv[nf]);
    }
}

// ---------------- fallback fused 128x128 bf16 kernel (ws too small) ---------
__global__ __launch_bounds__(256, 3) void gemm_fused_kernel(
    const float* __restrict__ x, const uint32_t* __restrict__ wq,
    const float* __restrict__ scales, const float* __restrict__ zeros,
    const float* __restrict__ bias, float* __restrict__ out) {
  __shared__ __align__(16) char smem[2 * 128 * 64 * 2];
  char* As = smem;
  char* Bs = smem + 16384;

  const int tid  = threadIdx.x;
  const int lane = tid & 63;
  const int wave = tid >> 6;
  const int wm = wave >> 1, wn = wave & 1;

  const int b   = blockIdx.x;
  const int swz = (b & 7) * 344 + (b >> 3);
  const int mt  = swz / 86;
  const int nt  = swz - mt * 86;
  const int bm0 = mt * 128, bn0 = nt * 128;

  f32x4 acc[4][4];
#pragma unroll
  for (int i = 0; i < 4; ++i)
#pragma unroll
    for (int j = 0; j < 4; ++j) acc[i][j] = (f32x4){0.f, 0.f, 0.f, 0.f};

  const int base_a = ((wm * 64 + (lane & 15)) << 7) + ((lane >> 4) << 4);
  const int base_b = ((wn * 64 + (lane & 15)) << 7) + ((lane >> 4) << 4);

  float sv[4], zv[4];
#pragma unroll
  for (int it = 0; it < 4; ++it) {
    int r = bn0 + it * 32 + (tid >> 3);
    sv[it] = bf16r(scales[r]);
    zv[it] = bf16r(zeros[r]);
  }

  for (int kt = 0; kt < KDIM / 64; ++kt) {
    const int k0 = kt * 64;
    __syncthreads();
#pragma unroll
    for (int it = 0; it < 4; ++it) {
      int ch = it * 256 + tid;
      int row = ch >> 3, c8 = ch & 7;
      const float* src = x + (size_t)(bm0 + row) * KDIM + k0 + c8 * 8;
      float4 f0 = *(const float4*)src;
      float4 f1 = *(const float4*)(src + 4);
      u16x8 v;
      v[0] = f2bf(f0.x); v[1] = f2bf(f0.y); v[2] = f2bf(f0.z); v[3] = f2bf(f0.w);
      v[4] = f2bf(f1.x); v[5] = f2bf(f1.y); v[6] = f2bf(f1.z); v[7] = f2bf(f1.w);
      *(u16x8*)(As + row * 128 + c8 * 16) = v;
    }
#pragma unroll
    for (int it = 0; it < 4; ++it) {
      int ch = it * 256 + tid;
      int row = ch >> 3, kp = ch & 7;
      uint32_t w = wq[(size_t)(bn0 + row) * KP + kt * 8 + kp];
      float s = sv[it], z = zv[it];
      u16x8 v;
#pragma unroll
      for (int j = 0; j < 8; ++j) {
        float qf = (float)((w >> (4 * j)) & 0xF);
        float t  = bf16r(qf * s);
        v[j] = f2bf(t + z);
      }
      *(u16x8*)(Bs + row * 128 + kp * 16) = v;
    }
    __syncthreads();
#pragma unroll
    for (int ks = 0; ks < 2; ++ks) {
      bf16x8 af[4], bf[4];
#pragma unroll
      for (int i = 0; i < 4; ++i)
        af[i] = *(const bf16x8*)(As + base_a + i * 2048 + ks * 64);
#pragma unroll
      for (int j = 0; j < 4; ++j)
        bf[j] = *(const bf16x8*)(Bs + base_b + j * 2048 + ks * 64);
#pragma unroll
      for (int i = 0; i < 4; ++i)
#pragma unroll
        for (int j = 0; j < 4; ++j)
          acc[i][j] = __builtin_amdgcn_mfma_f32_16x16x32_bf16(af[i], bf[j],
                                                              acc[i][j], 0, 0, 0);
    }
  }

  const int colbase = bn0 + wn * 64 + (lane & 15);
  const int rowbase = bm0 + wm * 64 + ((lane >> 4) << 2);
  float bv[4];
#pragma unroll
  for (int j = 0; j < 4; ++j) bv[j] = bias[colbase + j * 16];
#pragma unroll
  for (int i = 0; i < 4; ++i) {
#pragma unroll
    for (int j = 0; j < 4; ++j) {
      size_t base = (size_t)(rowbase + i * 16) * NDIM + colbase + j * 16;
#pragma unroll
      for (int r = 0; r < 4; ++r)
        out[base + (size_t)r * NDIM] = acc[i][j][r] + bv[j];
    }
  }
}

extern "C" void kernel_launch(void* const* d_in, const int* in_sizes, int n_in,
                              void* d_out, int out_size, void* d_ws, size_t ws_size,
                              hipStream_t stream) {
  const float*    x      = (const float*)d_in[0];
  const uint32_t* wq     = (const uint32_t*)d_in[1];
  const float*    scales = (const float*)d_in[2];
  const float*    zeros  = (const float*)d_in[3];
  const float*    bias   = (const float*)d_in[4];
  float*          out    = (float*)d_out;

  const size_t offQ = 0;
  const size_t szQ  = (size_t)NDIM * KDIM;           // 45,088,768
  const size_t offX = szQ;
  const size_t szX  = (size_t)MDIM * KDIM;           // 16,777,216
  const size_t offD = offX + szX;                    // 61,865,984
  const size_t offS = offD + MDIM * sizeof(float);
  const size_t need = offS + MDIM * sizeof(float);   // ~61.9 MB

  if (ws_size >= need) {
    char*  Q8    = (char*)d_ws + offQ;
    char*  X8    = (char*)d_ws + offX;
    float* dlt   = (float*)((char*)d_ws + offD);
    float* xsm   = (float*)((char*)d_ws + offS);
    repack_q_kernel<<<(NDIM * KP) / 256, 256, 0, stream>>>(wq, (c8x8*)Q8);
    quant_x_kernel<<<MDIM, 256, 0, stream>>>(x, (c8x16*)X8, dlt, xsm);
    gemm_i8_kernel<<<688, 256, 0, stream>>>(X8, Q8, dlt, xsm, scales, zeros,
                                            bias, out);
  } else {
    gemm_fused_kernel<<<2752, 256, 0, stream>>>(x, wq, scales, zeros, bias, out);
  }
}

// Round 16
// 239.831 us; speedup vs baseline: 9.6144x; 9.6144x over previous
//
#include <hip/hip_runtime.h>
#include <stdint.h>

#define MDIM 4096
#define KDIM 4096
#define NDIM 11008
#define KP   (KDIM/8)    // 512 packed int32 per N-row

typedef float  f32x4   __attribute__((ext_vector_type(4)));
typedef __bf16 bf16x8  __attribute__((ext_vector_type(8)));
typedef unsigned short u16x8 __attribute__((ext_vector_type(8)));
typedef int    i32x4   __attribute__((ext_vector_type(4)));
typedef int    i32x16  __attribute__((ext_vector_type(16)));
typedef char   c8x8    __attribute__((ext_vector_type(8)));
typedef char   c8x16   __attribute__((ext_vector_type(16)));

// RNE f32 -> bf16 bits (matches jax astype(bf16) for non-NaN inputs)
__device__ __forceinline__ unsigned short f2bf(float f) {
  uint32_t u = __builtin_bit_cast(uint32_t, f);
  u += 0x7FFFu + ((u >> 16) & 1u);
  return (unsigned short)(u >> 16);
}
__device__ __forceinline__ float bf2f(unsigned short h) {
  return __builtin_bit_cast(float, (uint32_t)h << 16);
}
__device__ __forceinline__ float bf16r(float f) { return bf2f(f2bf(f)); }

// async global -> LDS, 16B per lane, wave-uniform LDS base + lane*16
__device__ __forceinline__ void lds16(const void* g, void* l) {
  __builtin_amdgcn_global_load_lds(
      (const __attribute__((address_space(1))) unsigned int*)g,
      (__attribute__((address_space(3))) unsigned int*)l, 16, 0, 0);
}

// ---------------- pre-pass 1: unpack int4 words -> int8 Q8[N][K] ------------
__global__ __launch_bounds__(256) void repack_q_kernel(
    const uint32_t* __restrict__ wq, c8x8* __restrict__ Q8) {
  int idx = blockIdx.x * 256 + threadIdx.x;   // [0, N*KP)
  uint32_t w = wq[idx];
  c8x8 v;
#pragma unroll
  for (int j = 0; j < 8; ++j) v[j] = (char)((w >> (4 * j)) & 0xF);
  Q8[idx] = v;
}

// ---------------- pre-pass 2: x f32 -> per-row int8 + delta + exact bf16 sum
__global__ __launch_bounds__(256) void quant_x_kernel(
    const float* __restrict__ x, c8x16* __restrict__ X8,
    float* __restrict__ delta, float* __restrict__ xsum) {
  __shared__ float red[256];
  const int row = blockIdx.x, t = threadIdx.x;
  const float4* xr = (const float4*)(x + (size_t)row * KDIM);
  float xb[16];
#pragma unroll
  for (int i = 0; i < 4; ++i) {
    float4 f = xr[t * 4 + i];
    xb[i * 4 + 0] = bf16r(f.x); xb[i * 4 + 1] = bf16r(f.y);
    xb[i * 4 + 2] = bf16r(f.z); xb[i * 4 + 3] = bf16r(f.w);
  }
  float mx = 0.f, sm = 0.f;
#pragma unroll
  for (int j = 0; j < 16; ++j) { mx = fmaxf(mx, fabsf(xb[j])); sm += xb[j]; }
  red[t] = mx; __syncthreads();
  for (int o = 128; o > 0; o >>= 1) {
    if (t < o) red[t] = fmaxf(red[t], red[t + o]);
    __syncthreads();
  }
  const float rmx = red[0];
  __syncthreads();
  red[t] = sm; __syncthreads();
  for (int o = 128; o > 0; o >>= 1) {
    if (t < o) red[t] += red[t + o];
    __syncthreads();
  }
  const float rsm = red[0];
  const float inv = (rmx > 0.f) ? 127.0f / rmx : 0.f;
  if (t == 0) {
    delta[row] = (rmx > 0.f) ? rmx / 127.0f : 0.f;
    xsum[row]  = rsm;
  }
  c8x16 q;
#pragma unroll
  for (int j = 0; j < 16; ++j) q[j] = (char)__float2int_rn(xb[j] * inv);
  X8[(size_t)row * 256 + t] = q;
}

// ---------------- main GEMM: 256x128 tile, 4 waves, i8 32x32x32, 2 blk/CU ---
// The feasible 2-blocks/CU config (r15 post-mortem): acc must fit 256-reg cap
// at 2 waves/SIMD -> per-wave output 128x64 (acc[4][2] = 128 regs). r12
// PROVED the 2-block overlap mechanism (its wall == LDS-pipe time exactly,
// MFMA fully hidden); it lost only on LDS oversubscription (reads/MFMA=1.0).
// This geometry: reads/MFMA = 0.75 -> per-CU LDS ~2700 cyc vs MFMA 2066 per
// 256x256-worth -> wall ~= max ~= 2700 (r10's serialized wall was 5030).
// Tile 256Mx128N, BK=128, 4 waves (2Mx2N). 3-slot ring, slot = 24KB
// (A 16KB | B 8KB), 72KB LDS total -> 2 blocks/CU via launch_bounds(256,2).
// Schedule = r12's PASSING 4-phase TILE, scaled: stage-half = 6 loads
// (A:4 + B:2), loads/phase [4,2,4,2]. Trace: prologue 18 loads VMWAIT(12);
// steady enter-tile 6 outstanding; p1 VMWAIT(6) retires (T,h1) (first read
// p2); p3 VMWAIT(6) retires (T+1,h0) (first read next p0); tail T31
// VMWAIT(0)@p1. Every read covered by a wait+barrier one phase earlier
// (r8/r10/r12 invariant). WAR slot-recycle one-barrier separation holds.
// Staging/read addressing verbatim r12/r13 (0-conflict measured).
__global__ __launch_bounds__(256, 2) void gemm_i8_kernel(
    const char* __restrict__ A8, const char* __restrict__ Q8,
    const float* __restrict__ delta, const float* __restrict__ xsum,
    const float* __restrict__ scales, const float* __restrict__ zeros,
    const float* __restrict__ bias, float* __restrict__ out) {
  __shared__ __align__(16) char smem[73728];   // 3 slots x (A 16KB | B 8KB)

  const int tid  = threadIdx.x;
  const int lane = tid & 63;
  const int wave = tid >> 6;     // 0..3
  const int wm   = wave >> 1;    // 0..1 : M half (128 rows)
  const int wn   = wave & 1;     // 0..1 : N half (64 cols)

  // XCD-aware bijective swizzle: 1376 = 8 * 172; consecutive swz share mt
  // (86 n-tiles per m-tile) -> A panel L2 reuse.
  const int b   = blockIdx.x;
  const int swz = (b & 7) * 172 + (b >> 3);
  const int mt  = swz / 86;
  const int nt  = swz - mt * 86;
  const int bm0 = mt * 256, bn0 = nt * 128;

  // staging (r13/r12 pattern): lane l writes subtile bytes [l*16,+16);
  // stored position schunk holds global chunk schunk ^ (b3(srow)<<1) ^ parity.
  const int srow   = lane >> 2;
  const int schunk = lane & 3;
  const int p0c    = schunk ^ (((srow >> 3) & 1) << 1);
  // A: wave stages subtiles 4*wave+j (j=0..3, parity j&1) = rows wave*64..+64
  const char* aRe = A8 + (size_t)(bm0 + wave * 64 + srow) * KDIM + (size_t)(p0c * 16);
  const char* aRo = A8 + (size_t)(bm0 + wave * 64 + srow) * KDIM + (size_t)((p0c ^ 1) * 16);
  // B: wave stages subtiles 2*wave (parity 0) and 2*wave+1 (parity 1)
  const char* bRe = Q8 + (size_t)(bn0 + wave * 32 + srow) * KDIM + (size_t)(p0c * 16);
  const char* bRo = Q8 + (size_t)(bn0 + wave * 32 + 16 + srow) * KDIM + (size_t)((p0c ^ 1) * 16);

  // fragment read offsets (r10-proven zero-conflict pattern)
  const int r31 = lane & 31;
  const int sub = r31 >> 4;
  const int r15 = r31 & 15;
  const int hk  = lane >> 5;
  const int rd0 = sub * 1024 + r15 * 64 + ((hk ^ sub) << 4) + ((r15 & 8) << 2);
  const int rd1 = rd0 ^ 32;

  i32x16 acc[4][2];
#pragma unroll
  for (int i = 0; i < 4; ++i)
#pragma unroll
    for (int j = 0; j < 2; ++j)
#pragma unroll
      for (int r = 0; r < 16; ++r) acc[i][j][r] = 0;

  i32x4 Af[4], Bf[2];

#define SLOTB(S) ((S) * 24576)

// stage A-half (16KB = 16 subtiles) of (t,h) into slot S: 4 lds16/wave
#define STAGE_A(t, h, S)                                                    \
  do {                                                                      \
    const size_t ko_ = (size_t)(t) * 128 + (size_t)(h) * 64;                \
    char* d_ = smem + SLOTB(S) + wave * 4096;                               \
    _Pragma("unroll") for (int j = 0; j < 4; ++j)                           \
      lds16(((j & 1) ? aRo : aRe) + (size_t)j * 16 * KDIM + ko_,            \
            d_ + j * 1024);                                                 \
  } while (0)

// stage B-half (8KB = 8 subtiles) of (t,h) into slot S: 2 lds16/wave
#define STAGE_B(t, h, S)                                                    \
  do {                                                                      \
    const size_t ko_ = (size_t)(t) * 128 + (size_t)(h) * 64;                \
    char* d_ = smem + SLOTB(S) + 16384 + wave * 2048;                       \
    lds16(bRe + ko_, d_);                                                   \
    lds16(bRo + ko_, d_ + 1024);                                            \
  } while (0)

#define READ6(S, KS)                                                        \
  do {                                                                      \
    const int ro_ = (KS) ? rd1 : rd0;                                       \
    _Pragma("unroll") for (int mf = 0; mf < 4; ++mf)                        \
        Af[mf] = *(const i32x4*)(smem + SLOTB(S) + wm * 8192 +              \
                                 mf * 2048 + ro_);                          \
    _Pragma("unroll") for (int nf = 0; nf < 2; ++nf)                        \
        Bf[nf] = *(const i32x4*)(smem + SLOTB(S) + 16384 + wn * 4096 +      \
                                 nf * 2048 + ro_);                          \
  } while (0)

#define MFMA8()                                                             \
  __builtin_amdgcn_s_setprio(1);                                            \
  _Pragma("unroll") for (int mf = 0; mf < 4; ++mf)                          \
      _Pragma("unroll") for (int nf = 0; nf < 2; ++nf)                      \
          acc[mf][nf] = __builtin_amdgcn_mfma_i32_32x32x32_i8(              \
              Af[mf], Bf[nf], acc[mf][nf], 0, 0, 0);                        \
  __builtin_amdgcn_s_setprio(0);

#define BAR                                                                 \
  __builtin_amdgcn_s_barrier();                                             \
  __builtin_amdgcn_sched_barrier(0);

#define VMWAIT(N) asm volatile("s_waitcnt vmcnt(" #N ")" ::: "memory")

  // TILE (r12's passing schedule): S0/S1 = slots of (T,h0)/(T,h1);
  // SA = slot for (T+1,h0); (T+1,h1) -> S0 (recycled, one-barrier WAR sep).
#define TILE(T, S0, S1, SA, STG01, STG23, VM1STMT, VM3STMT)                 \
  do {                                                                      \
    READ6(S0, 0);                                                           \
    if (STG01) STAGE_A((T) + 1, 0, SA);                                     \
    BAR; MFMA8(); BAR;                                                      \
    READ6(S0, 1);                                                           \
    if (STG01) STAGE_B((T) + 1, 0, SA);                                     \
    VM1STMT;                                                                \
    BAR; MFMA8(); BAR;                                                      \
    READ6(S1, 0);                                                           \
    if (STG23) STAGE_A((T) + 1, 1, S0);                                     \
    BAR; MFMA8(); BAR;                                                      \
    READ6(S1, 1);                                                           \
    if (STG23) STAGE_B((T) + 1, 1, S0);                                     \
    VM3STMT;                                                                \
    BAR; MFMA8(); BAR;                                                      \
  } while (0)

  // prologue: (0,h0)->slot0, (0,h1)->slot1, (1,h0)->slot2 = 18 loads;
  // retire the first 6 ((0,h0) ready).
  STAGE_A(0, 0, 0); STAGE_B(0, 0, 0);
  STAGE_A(0, 1, 1); STAGE_B(0, 1, 1);
  STAGE_A(1, 0, 2); STAGE_B(1, 0, 2);
  VMWAIT(12);
  BAR;

  // T=0: (1,h0) already staged -> STG01=0; stage only (1,h1)->slot0.
  // p1 VMWAIT(6) retires (0,h1) before p2; p3 VMWAIT(6) retires (1,h0).
  TILE(0, 0, 1, 2, 0, 1, VMWAIT(6), VMWAIT(6));
  // T = 1..30, slot pattern period 3: T%3==1:(2,0,1); ==2:(1,2,0); ==0:(0,1,2)
  for (int tt = 1; tt < 28; tt += 3) {
    TILE(tt,     2, 0, 1, 1, 1, VMWAIT(6), VMWAIT(6));
    TILE(tt + 1, 1, 2, 0, 1, 1, VMWAIT(6), VMWAIT(6));
    TILE(tt + 2, 0, 1, 2, 1, 1, VMWAIT(6), VMWAIT(6));
  }
  TILE(28, 2, 0, 1, 1, 1, VMWAIT(6), VMWAIT(6));
  TILE(29, 1, 2, 0, 1, 1, VMWAIT(6), VMWAIT(6));
  TILE(30, 0, 1, 2, 1, 1, VMWAIT(6), VMWAIT(6));  // stages (31,h0)->2,(31,h1)->0
  TILE(31, 2, 0, 1, 0, 0, VMWAIT(0), (void)0);    // drain (31,h1) before p2

#undef TILE
#undef VMWAIT
#undef BAR
#undef MFMA8
#undef READ6
#undef STAGE_B
#undef STAGE_A
#undef SLOTB

  // epilogue: C/D 32x32 layout col=lane&31, row=(reg&3)+8*(reg>>2)+4*(lane>>5)
  // out = acc * (Delta_m * bf16(s_n)) + bf16(z_n) * xsum_m + bias_n
  const int colv = bn0 + wn * 64 + (lane & 31);
  const int rowb = bm0 + wm * 128 + ((lane >> 5) << 2);
  float sb[2], zb[2], bv[2];
#pragma unroll
  for (int nf = 0; nf < 2; ++nf) {
    sb[nf] = bf16r(scales[colv + nf * 32]);
    zb[nf] = bf16r(zeros[colv + nf * 32]);
    bv[nf] = bias[colv + nf * 32];
  }
#pragma unroll
  for (int mf = 0; mf < 4; ++mf)
#pragma unroll
    for (int reg = 0; reg < 16; ++reg) {
      const int row = rowb + mf * 32 + (reg & 3) + ((reg >> 2) << 3);
      const float dm = delta[row];
      const float xm = xsum[row];
#pragma unroll
      for (int nf = 0; nf < 2; ++nf)
        out[(size_t)row * NDIM + colv + nf * 32] =
            (float)acc[mf][nf][reg] * (dm * sb[nf]) + (zb[nf] * xm + bv[nf]);
    }
}

// ---------------- fallback fused 128x128 bf16 kernel (ws too small) ---------
__global__ __launch_bounds__(256, 3) void gemm_fused_kernel(
    const float* __restrict__ x, const uint32_t* __restrict__ wq,
    const float* __restrict__ scales, const float* __restrict__ zeros,
    const float* __restrict__ bias, float* __restrict__ out) {
  __shared__ __align__(16) char smem[2 * 128 * 64 * 2];
  char* As = smem;
  char* Bs = smem + 16384;

  const int tid  = threadIdx.x;
  const int lane = tid & 63;
  const int wave = tid >> 6;
  const int wm = wave >> 1, wn = wave & 1;

  const int b   = blockIdx.x;
  const int swz = (b & 7) * 344 + (b >> 3);
  const int mt  = swz / 86;
  const int nt  = swz - mt * 86;
  const int bm0 = mt * 128, bn0 = nt * 128;

  f32x4 acc[4][4];
#pragma unroll
  for (int i = 0; i < 4; ++i)
#pragma unroll
    for (int j = 0; j < 4; ++j) acc[i][j] = (f32x4){0.f, 0.f, 0.f, 0.f};

  const int base_a = ((wm * 64 + (lane & 15)) << 7) + ((lane >> 4) << 4);
  const int base_b = ((wn * 64 + (lane & 15)) << 7) + ((lane >> 4) << 4);

  float sv[4], zv[4];
#pragma unroll
  for (int it = 0; it < 4; ++it) {
    int r = bn0 + it * 32 + (tid >> 3);
    sv[it] = bf16r(scales[r]);
    zv[it] = bf16r(zeros[r]);
  }

  for (int kt = 0; kt < KDIM / 64; ++kt) {
    const int k0 = kt * 64;
    __syncthreads();
#pragma unroll
    for (int it = 0; it < 4; ++it) {
      int ch = it * 256 + tid;
      int row = ch >> 3, c8 = ch & 7;
      const float* src = x + (size_t)(bm0 + row) * KDIM + k0 + c8 * 8;
      float4 f0 = *(const float4*)src;
      float4 f1 = *(const float4*)(src + 4);
      u16x8 v;
      v[0] = f2bf(f0.x); v[1] = f2bf(f0.y); v[2] = f2bf(f0.z); v[3] = f2bf(f0.w);
      v[4] = f2bf(f1.x); v[5] = f2bf(f1.y); v[6] = f2bf(f1.z); v[7] = f2bf(f1.w);
      *(u16x8*)(As + row * 128 + c8 * 16) = v;
    }
#pragma unroll
    for (int it = 0; it < 4; ++it) {
      int ch = it * 256 + tid;
      int row = ch >> 3, kp = ch & 7;
      uint32_t w = wq[(size_t)(bn0 + row) * KP + kt * 8 + kp];
      float s = sv[it], z = zv[it];
      u16x8 v;
#pragma unroll
      for (int j = 0; j < 8; ++j) {
        float qf = (float)((w >> (4 * j)) & 0xF);
        float t  = bf16r(qf * s);
        v[j] = f2bf(t + z);
      }
      *(u16x8*)(Bs + row * 128 + kp * 16) = v;
    }
    __syncthreads();
#pragma unroll
    for (int ks = 0; ks < 2; ++ks) {
      bf16x8 af[4], bf[4];
#pragma unroll
      for (int i = 0; i < 4; ++i)
        af[i] = *(const bf16x8*)(As + base_a + i * 2048 + ks * 64);
#pragma unroll
      for (int j = 0; j < 4; ++j)
        bf[j] = *(const bf16x8*)(Bs + base_b + j * 2048 + ks * 64);
#pragma unroll
      for (int i = 0; i < 4; ++i)
#pragma unroll
        for (int j = 0; j < 4; ++j)
          acc[i][j] = __builtin_amdgcn_mfma_f32_16x16x32_bf16(af[i], bf[j],
                                                              acc[i][j], 0, 0, 0);
    }
  }

  const int colbase = bn0 + wn * 64 + (lane & 15);
  const int rowbase = bm0 + wm * 64 + ((lane >> 4) << 2);
  float bv[4];
#pragma unroll
  for (int j = 0; j < 4; ++j) bv[j] = bias[colbase + j * 16];
#pragma unroll
  for (int i = 0; i < 4; ++i) {
#pragma unroll
    for (int j = 0; j < 4; ++j) {
      size_t base = (size_t)(rowbase + i * 16) * NDIM + colbase + j * 16;
#pragma unroll
      for (int r = 0; r < 4; ++r)
        out[base + (size_t)r * NDIM] = acc[i][j][r] + bv[j];
    }
  }
}

extern "C" void kernel_launch(void* const* d_in, const int* in_sizes, int n_in,
                              void* d_out, int out_size, void* d_ws, size_t ws_size,
                              hipStream_t stream) {
  const float*    x      = (const float*)d_in[0];
  const uint32_t* wq     = (const uint32_t*)d_in[1];
  const float*    scales = (const float*)d_in[2];
  const float*    zeros  = (const float*)d_in[3];
  const float*    bias   = (const float*)d_in[4];
  float*          out    = (float*)d_out;

  const size_t offQ = 0;
  const size_t szQ  = (size_t)NDIM * KDIM;           // 45,088,768
  const size_t offX = szQ;
  const size_t szX  = (size_t)MDIM * KDIM;           // 16,777,216
  const size_t offD = offX + szX;                    // 61,865,984
  const size_t offS = offD + MDIM * sizeof(float);
  const size_t need = offS + MDIM * sizeof(float);   // ~61.9 MB

  if (ws_size >= need) {
    char*  Q8    = (char*)d_ws + offQ;
    char*  X8    = (char*)d_ws + offX;
    float* dlt   = (float*)((char*)d_ws + offD);
    float* xsm   = (float*)((char*)d_ws + offS);
    repack_q_kernel<<<(NDIM * KP) / 256, 256, 0, stream>>>(wq, (c8x8*)Q8);
    quant_x_kernel<<<MDIM, 256, 0, stream>>>(x, (c8x16*)X8, dlt, xsm);
    gemm_i8_kernel<<<1376, 256, 0, stream>>>(X8, Q8, dlt, xsm, scales, zeros,
                                             bias, out);
  } else {
    gemm_fused_kernel<<<2752, 256, 0, stream>>>(x, wq, scales, zeros, bias, out);
  }
}

// Round 17
// 229.267 us; speedup vs baseline: 10.0574x; 1.0461x over previous
//
#include <hip/hip_runtime.h>
#include <stdint.h>

#define MDIM 4096
#define KDIM 4096
#define NDIM 11008
#define KP   (KDIM/8)    // 512 packed int32 per N-row
#define NQB  (NDIM*KP/256)   // 22016 repack blocks

typedef float  f32x4   __attribute__((ext_vector_type(4)));
typedef __bf16 bf16x8  __attribute__((ext_vector_type(8)));
typedef unsigned short u16x8 __attribute__((ext_vector_type(8)));
typedef int    i32x4   __attribute__((ext_vector_type(4)));
typedef int    i32x16  __attribute__((ext_vector_type(16)));
typedef char   c8x8    __attribute__((ext_vector_type(8)));
typedef char   c8x16   __attribute__((ext_vector_type(16)));

// RNE f32 -> bf16 bits (matches jax astype(bf16) for non-NaN inputs)
__device__ __forceinline__ unsigned short f2bf(float f) {
  uint32_t u = __builtin_bit_cast(uint32_t, f);
  u += 0x7FFFu + ((u >> 16) & 1u);
  return (unsigned short)(u >> 16);
}
__device__ __forceinline__ float bf2f(unsigned short h) {
  return __builtin_bit_cast(float, (uint32_t)h << 16);
}
__device__ __forceinline__ float bf16r(float f) { return bf2f(f2bf(f)); }

// async global -> LDS, 16B per lane, wave-uniform LDS base + lane*16
__device__ __forceinline__ void lds16(const void* g, void* l) {
  __builtin_amdgcn_global_load_lds(
      (const __attribute__((address_space(1))) unsigned int*)g,
      (__attribute__((address_space(3))) unsigned int*)l, 16, 0, 0);
}

// ---------------- fused pre-pass: repack W + quantize X in ONE dispatch -----
// blocks [0, NQB): unpack int4 words -> int8 Q8[N][K] (one thread/word).
// blocks [NQB, NQB+MDIM): per-row x quant -> X8 + delta + exact bf16 row-sum.
// The two workloads are independent; fusing lets them overlap on the chip
// (previously serialized by the stream) and saves one launch overhead.
__global__ __launch_bounds__(256) void prepass_kernel(
    const uint32_t* __restrict__ wq, c8x8* __restrict__ Q8,
    const float* __restrict__ x, c8x16* __restrict__ X8,
    float* __restrict__ delta, float* __restrict__ xsum) {
  __shared__ float red[256];
  const int blk = blockIdx.x, t = threadIdx.x;
  if (blk < NQB) {
    int idx = blk * 256 + t;                  // [0, N*KP)
    uint32_t w = wq[idx];
    c8x8 v;
#pragma unroll
    for (int j = 0; j < 8; ++j) v[j] = (char)((w >> (4 * j)) & 0xF);
    Q8[idx] = v;
    return;
  }
  const int row = blk - NQB;
  const float4* xr = (const float4*)(x + (size_t)row * KDIM);
  float xb[16];
#pragma unroll
  for (int i = 0; i < 4; ++i) {
    float4 f = xr[t * 4 + i];
    xb[i * 4 + 0] = bf16r(f.x); xb[i * 4 + 1] = bf16r(f.y);
    xb[i * 4 + 2] = bf16r(f.z); xb[i * 4 + 3] = bf16r(f.w);
  }
  float mx = 0.f, sm = 0.f;
#pragma unroll
  for (int j = 0; j < 16; ++j) { mx = fmaxf(mx, fabsf(xb[j])); sm += xb[j]; }
  red[t] = mx; __syncthreads();
  for (int o = 128; o > 0; o >>= 1) {
    if (t < o) red[t] = fmaxf(red[t], red[t + o]);
    __syncthreads();
  }
  const float rmx = red[0];
  __syncthreads();
  red[t] = sm; __syncthreads();
  for (int o = 128; o > 0; o >>= 1) {
    if (t < o) red[t] += red[t + o];
    __syncthreads();
  }
  const float rsm = red[0];
  const float inv = (rmx > 0.f) ? 127.0f / rmx : 0.f;
  if (t == 0) {
    delta[row] = (rmx > 0.f) ? rmx / 127.0f : 0.f;
    xsum[row]  = rsm;
  }
  c8x16 q;
#pragma unroll
  for (int j = 0; j < 16; ++j) q[j] = (char)__float2int_rn(xb[j] * inv);
  X8[(size_t)row * 256 + t] = q;
}

// ---------------- main GEMM: 256x256, BK=128, 8 waves, i8 32x32x32 ----------
// VERBATIM round-10 winner (GEMM 193us, MfmaUtil 43%, 0 bank conflicts):
// 4-slot K-half ring (A 4x16KB at 0, B at +64KB), 4-phase TILE with counted
// VMWAIT(8) (waits one phase before the dependent read, one-barrier WAR
// separation on slot recycle), chunk-permutation selector b3 (the proven
// zero-conflict read pattern), XCD-bijective block swizzle.
// Structure-space note (r11-r16): 2-blk/CU, barrier-free, 4-wave, and
// 256x128 variants all measured 200-250us or failed; 1 blk/CU here is
// register-forced (acc 128 + ~104 arch regs -> 8 waves/CU cap), and this
// config is the measured optimum of the family.
__global__ __launch_bounds__(512, 2) void gemm256_i8_kernel(
    const char* __restrict__ A8, const char* __restrict__ Q8,
    const float* __restrict__ delta, const float* __restrict__ xsum,
    const float* __restrict__ scales, const float* __restrict__ zeros,
    const float* __restrict__ bias, float* __restrict__ out) {
  __shared__ __align__(16) char smem[131072];

  const int tid  = threadIdx.x;
  const int lane = tid & 63;
  const int wave = tid >> 6;     // 0..7
  const int wm   = wave >> 2;    // 0..1 : M half (128 rows)
  const int wn   = wave & 3;     // 0..3 : N quarter (64 cols)

  // XCD-aware bijective swizzle: 688 = 8 * 86 blocks.
  const int b   = blockIdx.x;
  const int swz = (b & 7) * 86 + (b >> 3);
  const int mt  = swz / 43;
  const int nt  = swz - mt * 43;
  const int bm0 = mt * 256, bn0 = nt * 256;

  // staging geometry: lane l writes subtile bytes [l*16, l*16+16):
  // row srow = l>>2, stored position schunk = l&3; source global chunk =
  // schunk ^ (b3(srow)<<1) (^1 for the odd subtile).
  const int srow   = lane >> 2;
  const int schunk = lane & 3;
  const int perm0  = schunk ^ (((srow >> 3) & 1) << 1);
  const int perm1  = perm0 ^ 1;
  const char* aR  = A8 + (size_t)(bm0 + wave * 32 + srow) * KDIM + perm0 * 16;
  const char* aR2 = A8 + (size_t)(bm0 + wave * 32 + 16 + srow) * KDIM + perm1 * 16;
  const char* bR  = Q8 + (size_t)(bn0 + wave * 32 + srow) * KDIM + perm0 * 16;
  const char* bR2 = Q8 + (size_t)(bn0 + wave * 32 + 16 + srow) * KDIM + perm1 * 16;

  // fragment read offset for ks32 step s=0 (rd0) / s=1 (rd1 = rd0^32).
  // bank-quad bits: {bit6 = r15&1, bit5 = b3^s, bit4 = hk^sub} — the
  // r6-proven zero-conflict pattern.
  const int r31 = lane & 31;
  const int sub = r31 >> 4;
  const int r15 = r31 & 15;
  const int hk  = lane >> 5;
  const int rd0 = sub * 1024 + r15 * 64 + ((hk ^ sub) << 4) + ((r15 & 8) << 2);
  const int rd1 = rd0 ^ 32;

  const int aoffc = wm * 8192;          // wm*8 subtiles (128 rows)
  const int boffc = 65536 + wn * 4096;  // B ring + wn*4 subtiles (64 rows)

  i32x16 acc[4][2];
#pragma unroll
  for (int i = 0; i < 4; ++i)
#pragma unroll
    for (int j = 0; j < 2; ++j)
#pragma unroll
      for (int r = 0; r < 16; ++r) acc[i][j][r] = 0;

  i32x4 Af[4], Bf[2];

#define STAGE_A(tile, h, slot)                                              \
  do {                                                                      \
    const size_t ko_ = (size_t)((tile) * 128 + (h) * 64);                   \
    char* d_ = smem + ((slot) << 14) + wave * 2048;                         \
    lds16(aR + ko_, d_);                                                    \
    lds16(aR2 + ko_, d_ + 1024);                                            \
  } while (0)

#define STAGE_B(tile, h, slot)                                              \
  do {                                                                      \
    const size_t ko_ = (size_t)((tile) * 128 + (h) * 64);                   \
    char* d_ = smem + 65536 + ((slot) << 14) + wave * 2048;                 \
    lds16(bR + ko_, d_);                                                    \
    lds16(bR2 + ko_, d_ + 1024);                                            \
  } while (0)

#define READ6(slotbase, S)                                                  \
  do {                                                                      \
    const int ro_ = (S) ? rd1 : rd0;                                        \
    _Pragma("unroll") for (int mf = 0; mf < 4; ++mf)                        \
        Af[mf] = *(const i32x4*)(smem + aoffc + (slotbase) +                \
                                 mf * 2048 + ro_);                          \
    _Pragma("unroll") for (int nf = 0; nf < 2; ++nf)                        \
        Bf[nf] = *(const i32x4*)(smem + boffc + (slotbase) +                \
                                 nf * 2048 + ro_);                          \
  } while (0)

#define MFMA8()                                                             \
  __builtin_amdgcn_s_setprio(1);                                            \
  _Pragma("unroll") for (int mf = 0; mf < 4; ++mf)                          \
      _Pragma("unroll") for (int nf = 0; nf < 2; ++nf)                      \
          acc[mf][nf] = __builtin_amdgcn_mfma_i32_32x32x32_i8(              \
              Af[mf], Bf[nf], acc[mf][nf], 0, 0, 0);                        \
  __builtin_amdgcn_s_setprio(0);

#define BAR                                                                 \
  __builtin_amdgcn_s_barrier();                                             \
  __builtin_amdgcn_sched_barrier(0);

#define VMWAIT(N) asm volatile("s_waitcnt vmcnt(" #N ")" ::: "memory")

  // 4 phases/K-tile: (h0,s0),(h0,s1),(h1,s0),(h1,s1). Staging: p0 A(T+1,h1),
  // p1 B(T+1,h1) + VM, p2 A(T+2,h0)->S0s (recycle), p3 B(T+2,h0) + VM.
#define TILE(T, S0s, S1s, SN1s, NSTG, VM1STMT, VM3STMT)                     \
  do {                                                                      \
    READ6((S0s) << 14, 0);                                                  \
    if ((NSTG) >= 1) STAGE_A((T) + 1, 1, SN1s);                             \
    BAR; MFMA8(); BAR;                                                      \
    READ6((S0s) << 14, 1);                                                  \
    if ((NSTG) >= 2) STAGE_B((T) + 1, 1, SN1s);                             \
    VM1STMT;                                                                \
    BAR; MFMA8(); BAR;                                                      \
    READ6((S1s) << 14, 0);                                                  \
    if ((NSTG) >= 3) STAGE_A((T) + 2, 0, S0s);                              \
    BAR; MFMA8(); BAR;                                                      \
    READ6((S1s) << 14, 1);                                                  \
    if ((NSTG) >= 4) STAGE_B((T) + 2, 0, S0s);                              \
    VM3STMT;                                                                \
    BAR; MFMA8(); BAR;                                                      \
  } while (0)

  // prologue: (0,h0)->s0, (0,h1)->s1, (1,h0)->s2 = 12 loads; retire first 4
  STAGE_A(0, 0, 0);
  STAGE_B(0, 0, 0);
  STAGE_A(0, 1, 1);
  STAGE_B(0, 1, 1);
  STAGE_A(1, 0, 2);
  STAGE_B(1, 0, 2);
  VMWAIT(8);
  BAR;

  for (int tt = 0; tt < 30; tt += 2) {
    TILE(tt,     0, 1, 3, 4, VMWAIT(8), VMWAIT(8));
    TILE(tt + 1, 2, 3, 1, 4, VMWAIT(8), VMWAIT(8));
  }
  // T=30: stage only (31,h1); T=31: no staging, drain
  TILE(30, 0, 1, 3, 2, VMWAIT(8), VMWAIT(4));
  TILE(31, 2, 3, 1, 0, VMWAIT(0), (void)0);

#undef TILE
#undef VMWAIT
#undef BAR
#undef MFMA8
#undef READ6
#undef STAGE_B
#undef STAGE_A

  // epilogue: C/D 32x32 layout col=lane&31, row=(reg&3)+8*(reg>>2)+4*(lane>>5)
  // out = acc * (Delta_m * bf16(s_n)) + bf16(z_n) * xsum_m + bias_n
  const int colv = bn0 + wn * 64 + (lane & 31);
  const int rowb = bm0 + wm * 128 + ((lane >> 5) << 2);
  float sb[2], zb[2], bv[2];
#pragma unroll
  for (int nf = 0; nf < 2; ++nf) {
    sb[nf] = bf16r(scales[colv + nf * 32]);
    zb[nf] = bf16r(zeros[colv + nf * 32]);
    bv[nf] = bias[colv + nf * 32];
  }
#pragma unroll
  for (int mf = 0; mf < 4; ++mf)
#pragma unroll
    for (int reg = 0; reg < 16; ++reg) {
      const int row = rowb + mf * 32 + (reg & 3) + ((reg >> 2) << 3);
      const float dm = delta[row];
      const float xm = xsum[row];
#pragma unroll
      for (int nf = 0; nf < 2; ++nf)
        out[(size_t)row * NDIM + colv + nf * 32] =
            (float)acc[mf][nf][reg] * (dm * sb[nf]) + (zb[nf] * xm + bv[nf]);
    }
}

// ---------------- fallback fused 128x128 bf16 kernel (ws too small) ---------
__global__ __launch_bounds__(256, 3) void gemm_fused_kernel(
    const float* __restrict__ x, const uint32_t* __restrict__ wq,
    const float* __restrict__ scales, const float* __restrict__ zeros,
    const float* __restrict__ bias, float* __restrict__ out) {
  __shared__ __align__(16) char smem[2 * 128 * 64 * 2];
  char* As = smem;
  char* Bs = smem + 16384;

  const int tid  = threadIdx.x;
  const int lane = tid & 63;
  const int wave = tid >> 6;
  const int wm = wave >> 1, wn = wave & 1;

  const int b   = blockIdx.x;
  const int swz = (b & 7) * 344 + (b >> 3);
  const int mt  = swz / 86;
  const int nt  = swz - mt * 86;
  const int bm0 = mt * 128, bn0 = nt * 128;

  f32x4 acc[4][4];
#pragma unroll
  for (int i = 0; i < 4; ++i)
#pragma unroll
    for (int j = 0; j < 4; ++j) acc[i][j] = (f32x4){0.f, 0.f, 0.f, 0.f};

  const int base_a = ((wm * 64 + (lane & 15)) << 7) + ((lane >> 4) << 4);
  const int base_b = ((wn * 64 + (lane & 15)) << 7) + ((lane >> 4) << 4);

  float sv[4], zv[4];
#pragma unroll
  for (int it = 0; it < 4; ++it) {
    int r = bn0 + it * 32 + (tid >> 3);
    sv[it] = bf16r(scales[r]);
    zv[it] = bf16r(zeros[r]);
  }

  for (int kt = 0; kt < KDIM / 64; ++kt) {
    const int k0 = kt * 64;
    __syncthreads();
#pragma unroll
    for (int it = 0; it < 4; ++it) {
      int ch = it * 256 + tid;
      int row = ch >> 3, c8 = ch & 7;
      const float* src = x + (size_t)(bm0 + row) * KDIM + k0 + c8 * 8;
      float4 f0 = *(const float4*)src;
      float4 f1 = *(const float4*)(src + 4);
      u16x8 v;
      v[0] = f2bf(f0.x); v[1] = f2bf(f0.y); v[2] = f2bf(f0.z); v[3] = f2bf(f0.w);
      v[4] = f2bf(f1.x); v[5] = f2bf(f1.y); v[6] = f2bf(f1.z); v[7] = f2bf(f1.w);
      *(u16x8*)(As + row * 128 + c8 * 16) = v;
    }
#pragma unroll
    for (int it = 0; it < 4; ++it) {
      int ch = it * 256 + tid;
      int row = ch >> 3, kp = ch & 7;
      uint32_t w = wq[(size_t)(bn0 + row) * KP + kt * 8 + kp];
      float s = sv[it], z = zv[it];
      u16x8 v;
#pragma unroll
      for (int j = 0; j < 8; ++j) {
        float qf = (float)((w >> (4 * j)) & 0xF);
        float t  = bf16r(qf * s);
        v[j] = f2bf(t + z);
      }
      *(u16x8*)(Bs + row * 128 + kp * 16) = v;
    }
    __syncthreads();
#pragma unroll
    for (int ks = 0; ks < 2; ++ks) {
      bf16x8 af[4], bf[4];
#pragma unroll
      for (int i = 0; i < 4; ++i)
        af[i] = *(const bf16x8*)(As + base_a + i * 2048 + ks * 64);
#pragma unroll
      for (int j = 0; j < 4; ++j)
        bf[j] = *(const bf16x8*)(Bs + base_b + j * 2048 + ks * 64);
#pragma unroll
      for (int i = 0; i < 4; ++i)
#pragma unroll
        for (int j = 0; j < 4; ++j)
          acc[i][j] = __builtin_amdgcn_mfma_f32_16x16x32_bf16(af[i], bf[j],
                                                              acc[i][j], 0, 0, 0);
    }
  }

  const int colbase = bn0 + wn * 64 + (lane & 15);
  const int rowbase = bm0 + wm * 64 + ((lane >> 4) << 2);
  float bv[4];
#pragma unroll
  for (int j = 0; j < 4; ++j) bv[j] = bias[colbase + j * 16];
#pragma unroll
  for (int i = 0; i < 4; ++i) {
#pragma unroll
    for (int j = 0; j < 4; ++j) {
      size_t base = (size_t)(rowbase + i * 16) * NDIM + colbase + j * 16;
#pragma unroll
      for (int r = 0; r < 4; ++r)
        out[base + (size_t)r * NDIM] = acc[i][j][r] + bv[j];
    }
  }
}

extern "C" void kernel_launch(void* const* d_in, const int* in_sizes, int n_in,
                              void* d_out, int out_size, void* d_ws, size_t ws_size,
                              hipStream_t stream) {
  const float*    x      = (const float*)d_in[0];
  const uint32_t* wq     = (const uint32_t*)d_in[1];
  const float*    scales = (const float*)d_in[2];
  const float*    zeros  = (const float*)d_in[3];
  const float*    bias   = (const float*)d_in[4];
  float*          out    = (float*)d_out;

  const size_t offQ = 0;
  const size_t szQ  = (size_t)NDIM * KDIM;           // 45,088,768
  const size_t offX = szQ;
  const size_t szX  = (size_t)MDIM * KDIM;           // 16,777,216
  const size_t offD = offX + szX;                    // 61,865,984
  const size_t offS = offD + MDIM * sizeof(float);
  const size_t need = offS + MDIM * sizeof(float);   // ~61.9 MB

  if (ws_size >= need) {
    char*  Q8    = (char*)d_ws + offQ;
    char*  X8    = (char*)d_ws + offX;
    float* dlt   = (float*)((char*)d_ws + offD);
    float* xsm   = (float*)((char*)d_ws + offS);
    prepass_kernel<<<NQB + MDIM, 256, 0, stream>>>(wq, (c8x8*)Q8, x,
                                                   (c8x16*)X8, dlt, xsm);
    gemm256_i8_kernel<<<688, 512, 0, stream>>>(X8, Q8, dlt, xsm, scales, zeros,
                                               bias, out);
  } else {
    gemm_fused_kernel<<<2752, 256, 0, stream>>>(x, wq, scales, zeros, bias, out);
  }
}